// Round 1
// baseline (591.017 us; speedup 1.0000x reference)
//
#include <hip/hip_runtime.h>
#include <stdint.h>

typedef unsigned short u16;
typedef __bf16 bf16x8 __attribute__((ext_vector_type(8)));
typedef float f32x4 __attribute__((ext_vector_type(4)));

#define AS1 __attribute__((address_space(1)))
#define AS3 __attribute__((address_space(3)))

// async global->LDS, 16B per lane; LDS dest is wave-uniform base + lane*16
__device__ __forceinline__ void gload_lds16(u16* lds_wave_base, const u16* g) {
  __builtin_amdgcn_global_load_lds((AS1 void*)g, (AS3 void*)lds_wave_base, 16, 0, 0);
}

__device__ __forceinline__ u16 f2bf(float f) {  // RNE fp32->bf16
  unsigned int u = __float_as_uint(f);
  u += 0x7fffu + ((u >> 16) & 1u);
  return (u16)(u >> 16);
}

// ---------------- cast fp32 -> bf16, 8 elements/thread ----------------
__global__ void cast_f32_bf16(const float* __restrict__ in, u16* __restrict__ out, int n8) {
  int i = blockIdx.x * blockDim.x + threadIdx.x;
  if (i >= n8) return;
  const float4* p = (const float4*)in + (size_t)i * 2;
  float4 a = p[0], b = p[1];
  uint2 lo, hi;
  lo.x = (unsigned)f2bf(a.x) | ((unsigned)f2bf(a.y) << 16);
  lo.y = (unsigned)f2bf(a.z) | ((unsigned)f2bf(a.w) << 16);
  hi.x = (unsigned)f2bf(b.x) | ((unsigned)f2bf(b.y) << 16);
  hi.y = (unsigned)f2bf(b.z) | ((unsigned)f2bf(b.w) << 16);
  uint2* o = (uint2*)out + (size_t)i * 2;
  o[0] = lo;
  o[1] = hi;
}

// ---------------- generic C = A * B^T gemm, M,N mult of 128, K=512 ----------------
// A: [M][512] bf16 row-major, B: [N][512] bf16 row-major.
// MODE 0: G1a  A=x_bf (M=65536 tokens), B=w_qkv rows 0..1023 (N=1024).
//         store: QKt[bp][c][n] bf16, c=ncol, 4 consecutive tokens/lane. bias=b_qkv[c].
// MODE 1: G1b  A=w_qkv rows 1024..1535 (M=512 c'), B=x_bf (N=65536 tokens).
//         store: V[bp][n][c'] bf16, 4 consecutive c'/lane. bias=b_qkv[1024+c'].
// MODE 2: G2   A=Weff[bp] (M=512 co), B=V[bp] (N=4096 n), grid.z=bp.
//         store: y[bp][n][co] fp32 + b_out[co], 16B/lane.
template <int MODE>
__global__ __launch_bounds__(256) void gemm_bt(const u16* __restrict__ gA,
                                               const u16* __restrict__ gB,
                                               const float* __restrict__ bias,
                                               void* __restrict__ gC) {
  __shared__ __align__(16) u16 As[128 * 32];
  __shared__ __align__(16) u16 Bs[128 * 32];
  const int t = threadIdx.x;
  const int w = t >> 6, l = t & 63;
  const int lrow = l & 15, quad = l >> 4;
  const int wm = (w >> 1) * 64, wn = (w & 1) * 64;
  const int m0 = blockIdx.x * 128, n0 = blockIdx.y * 128;
  if (MODE == 2) {
    gA += (size_t)blockIdx.z * (512 * 512);
    gB += (size_t)blockIdx.z * (4096 * 512);
  }
  // staging geometry: wave w fills LDS rows [w*32, w*32+32), two 1KB issues
  const int srow = w * 32 + (l >> 2);
  const int scol = (l & 3) * 8;
  const u16* ga0 = gA + (size_t)(m0 + srow) * 512 + scol;
  const u16* ga1 = gA + (size_t)(m0 + srow + 16) * 512 + scol;
  const u16* gb0 = gB + (size_t)(n0 + srow) * 512 + scol;
  const u16* gb1 = gB + (size_t)(n0 + srow + 16) * 512 + scol;
  u16* lA0 = &As[w * 1024];
  u16* lA1 = &As[w * 1024 + 512];
  u16* lB0 = &Bs[w * 1024];
  u16* lB1 = &Bs[w * 1024 + 512];

  f32x4 acc[4][4];
#pragma unroll
  for (int mi = 0; mi < 4; ++mi)
#pragma unroll
    for (int ni = 0; ni < 4; ++ni) acc[mi][ni] = (f32x4){0.f, 0.f, 0.f, 0.f};

#pragma unroll 1
  for (int k0 = 0; k0 < 512; k0 += 32) {
    gload_lds16(lA0, ga0 + k0);
    gload_lds16(lA1, ga1 + k0);
    gload_lds16(lB0, gb0 + k0);
    gload_lds16(lB1, gb1 + k0);
    __syncthreads();
    bf16x8 af[4], bfr[4];
#pragma unroll
    for (int mi = 0; mi < 4; ++mi)
      af[mi] = *(const bf16x8*)&As[(wm + mi * 16 + lrow) * 32 + quad * 8];
#pragma unroll
    for (int ni = 0; ni < 4; ++ni)
      bfr[ni] = *(const bf16x8*)&Bs[(wn + ni * 16 + lrow) * 32 + quad * 8];
#pragma unroll
    for (int mi = 0; mi < 4; ++mi)
#pragma unroll
      for (int ni = 0; ni < 4; ++ni)
        acc[mi][ni] = __builtin_amdgcn_mfma_f32_16x16x32_bf16(af[mi], bfr[ni], acc[mi][ni], 0, 0, 0);
    __syncthreads();
  }

  // epilogue: D row (M-dim) = quad*4 + reg, col (N-dim) = lrow  [verified C/D layout]
#pragma unroll
  for (int mi = 0; mi < 4; ++mi) {
    const int mrow = m0 + wm + mi * 16 + quad * 4;
#pragma unroll
    for (int ni = 0; ni < 4; ++ni) {
      const int ncol = n0 + wn + ni * 16 + lrow;
      f32x4 v = acc[mi][ni];
      if (MODE == 0) {
        const int bp = mrow >> 12, n = mrow & 4095;
        const float bb = bias[ncol];
        uint2 pk;
        pk.x = (unsigned)f2bf(v[0] + bb) | ((unsigned)f2bf(v[1] + bb) << 16);
        pk.y = (unsigned)f2bf(v[2] + bb) | ((unsigned)f2bf(v[3] + bb) << 16);
        *(uint2*)((u16*)gC + (((size_t)bp << 22) + ((size_t)ncol << 12) + n)) = pk;
      } else if (MODE == 1) {
        const int bp = ncol >> 12, n = ncol & 4095;
        const float4 bb = *(const float4*)&bias[1024 + mrow];
        uint2 pk;
        pk.x = (unsigned)f2bf(v[0] + bb.x) | ((unsigned)f2bf(v[1] + bb.y) << 16);
        pk.y = (unsigned)f2bf(v[2] + bb.z) | ((unsigned)f2bf(v[3] + bb.w) << 16);
        *(uint2*)((u16*)gC + ((size_t)bp * (4096 * 512) + (size_t)n * 512 + mrow)) = pk;
      } else {
        const float4 bb = *(const float4*)&bias[mrow];
        float4 o;
        o.x = v[0] + bb.x;
        o.y = v[1] + bb.y;
        o.z = v[2] + bb.z;
        o.w = v[3] + bb.w;
        *(float4*)((float*)gC + (((size_t)blockIdx.z * 4096 + ncol) * 512 + mrow)) = o;
      }
    }
  }
}

// ---------------- per-(bp,h): L2 norms, QK^T, softmax, Weff = w_out_h @ attn ----------------
// QKt: [bp][1024][4096] bf16 (channels 0..511 = q, 512..1023 = k)
// Weff out: [bp][512 co][512 c] bf16, this block fills c in [h*64, h*64+64) for all co.
__global__ __launch_bounds__(512) void attn_weff(const u16* __restrict__ QKt,
                                                 const u16* __restrict__ wout,
                                                 const float* __restrict__ temperature,
                                                 u16* __restrict__ Weff) {
  __shared__ __align__(16) float sattn[64 * 64];
  __shared__ __align__(16) u16 sattnT[64 * 64];
  __shared__ float rn[128];
  const int blk = blockIdx.x;
  const int bp = blk >> 3, h = blk & 7;
  const int t = threadIdx.x, w = t >> 6, l = t & 63;
  const int lrow = l & 15, quad = l >> 4;
  const u16* base = QKt + ((size_t)bp << 22);

  // zero attn accumulator
  for (int i = t; i < 4096; i += 512) sattn[i] = 0.f;

  // row norms: rows 0..63 = q channels, 64..127 = k channels; wave w does 16 rows
#pragma unroll 1
  for (int rr = 0; rr < 16; ++rr) {
    const int i = w * 16 + rr;
    const int ch = (i < 64) ? (h * 64 + i) : (448 + h * 64 + i);
    const u16* row = base + ((size_t)ch << 12);
    float s = 0.f;
#pragma unroll
    for (int it = 0; it < 8; ++it) {
      bf16x8 a = *(const bf16x8*)(row + (it * 64 + l) * 8);
#pragma unroll
      for (int j = 0; j < 8; ++j) {
        float vv = (float)a[j];
        s += vv * vv;
      }
    }
#pragma unroll
    for (int off = 1; off < 64; off <<= 1) s += __shfl_xor(s, off);
    if (l == 0) rn[i] = 1.f / fmaxf(sqrtf(s), 1e-12f);
  }

  // QK^T: each wave covers a 512-token K-chunk; frags straight from global (L2-warm)
  f32x4 acc[4][4];
#pragma unroll
  for (int mi = 0; mi < 4; ++mi)
#pragma unroll
    for (int ni = 0; ni < 4; ++ni) acc[mi][ni] = (f32x4){0.f, 0.f, 0.f, 0.f};
  const u16* qb = base + ((size_t)(h * 64) << 12);
  const u16* kb = base + ((size_t)(512 + h * 64) << 12);
  const int nbase = w * 512;
#pragma unroll 1
  for (int ks = 0; ks < 16; ++ks) {
    const int nn = nbase + ks * 32 + quad * 8;
    bf16x8 af[4], bfr[4];
#pragma unroll
    for (int mi = 0; mi < 4; ++mi)
      af[mi] = *(const bf16x8*)(qb + (((size_t)(mi * 16 + lrow)) << 12) + nn);
#pragma unroll
    for (int ni = 0; ni < 4; ++ni)
      bfr[ni] = *(const bf16x8*)(kb + (((size_t)(ni * 16 + lrow)) << 12) + nn);
#pragma unroll
    for (int mi = 0; mi < 4; ++mi)
#pragma unroll
      for (int ni = 0; ni < 4; ++ni)
        acc[mi][ni] = __builtin_amdgcn_mfma_f32_16x16x32_bf16(af[mi], bfr[ni], acc[mi][ni], 0, 0, 0);
  }
  __syncthreads();  // zeroing + norms complete before accumulation
  // serialized cross-wave reduction into sattn (no LDS fp32 atomics risk)
  for (int ww = 0; ww < 8; ++ww) {
    if (w == ww) {
#pragma unroll
      for (int mi = 0; mi < 4; ++mi)
#pragma unroll
        for (int ni = 0; ni < 4; ++ni)
#pragma unroll
          for (int r = 0; r < 4; ++r)
            sattn[(mi * 16 + quad * 4 + r) * 64 + ni * 16 + lrow] += acc[mi][ni][r];
    }
    __syncthreads();
  }

  // normalize + temperature + softmax over e; write attn^T bf16 (A-operand layout for Weff)
  if (t < 64) {
    const int d = t;
    const float rq = rn[d];
    const float tmp = temperature[h];
    float mx = -1e30f;
    for (int e = 0; e < 64; ++e) {
      const int idx = (e + d) & 63;  // rotate to dodge bank conflicts
      float v = sattn[d * 64 + idx] * rq * rn[64 + idx] * tmp;
      sattn[d * 64 + idx] = v;
      mx = fmaxf(mx, v);
    }
    float s = 0.f;
    for (int e = 0; e < 64; ++e) {
      const int idx = (e + d) & 63;
      float p = __expf(sattn[d * 64 + idx] - mx);
      s += p;
      sattn[d * 64 + idx] = p;
    }
    const float inv = 1.f / s;
    for (int e = 0; e < 64; ++e) sattnT[e * 64 + d] = f2bf(sattn[d * 64 + e] * inv);
  }
  __syncthreads();

  // Weff_h: C[e][co] = sum_d attnT[e][d] * wout[co][h*64+d]  (M=64 e, N=512 co, K=64 d)
  bf16x8 a0[4], a1[4];
#pragma unroll
  for (int mi = 0; mi < 4; ++mi) {
    a0[mi] = *(const bf16x8*)&sattnT[(mi * 16 + lrow) * 64 + quad * 8];
    a1[mi] = *(const bf16x8*)&sattnT[(mi * 16 + lrow) * 64 + 32 + quad * 8];
  }
  u16* wb = Weff + ((size_t)bp * (512 * 512));
#pragma unroll 1
  for (int nb = 0; nb < 4; ++nb) {
    const int co = (w * 4 + nb) * 16 + lrow;
    const u16* wrow = wout + (size_t)co * 512 + h * 64;
    bf16x8 b0 = *(const bf16x8*)(wrow + quad * 8);
    bf16x8 b1 = *(const bf16x8*)(wrow + 32 + quad * 8);
#pragma unroll
    for (int mi = 0; mi < 4; ++mi) {
      f32x4 c = (f32x4){0.f, 0.f, 0.f, 0.f};
      c = __builtin_amdgcn_mfma_f32_16x16x32_bf16(a0[mi], b0, c, 0, 0, 0);
      c = __builtin_amdgcn_mfma_f32_16x16x32_bf16(a1[mi], b1, c, 0, 0, 0);
      const int e0 = mi * 16 + quad * 4;
      uint2 pk;
      pk.x = (unsigned)f2bf(c[0]) | ((unsigned)f2bf(c[1]) << 16);
      pk.y = (unsigned)f2bf(c[2]) | ((unsigned)f2bf(c[3]) << 16);
      *(uint2*)(wb + (size_t)co * 512 + h * 64 + e0) = pk;
    }
  }
}

extern "C" void kernel_launch(void* const* d_in, const int* in_sizes, int n_in,
                              void* d_out, int out_size, void* d_ws, size_t ws_size,
                              hipStream_t stream) {
  const float* x      = (const float*)d_in[0];  // (4,4,4096,512)
  const float* w_qkv  = (const float*)d_in[1];  // (1536,512)
  const float* b_qkv  = (const float*)d_in[2];  // (1536)
  const float* temp   = (const float*)d_in[3];  // (8,1,1)
  const float* w_out  = (const float*)d_in[4];  // (512,512)
  const float* b_out  = (const float*)d_in[5];  // (512)
  float* y = (float*)d_out;

  char* ws = (char*)d_ws;
  u16* x_bf    = (u16*)(ws);                         // 67,108,864 B
  u16* wqkv_bf = (u16*)(ws + 67108864);              //  1,572,864 B
  u16* wout_bf = (u16*)(ws + 68681728);              //    524,288 B
  u16* QKt     = (u16*)(ws + 69206016);              // 134,217,728 B
  u16* V_nat   = (u16*)(ws + 203423744);             // 67,108,864 B
  u16* Weff    = (u16*)(ws + 270532608);             //  8,388,608 B  (end 278,921,216)

  cast_f32_bf16<<<16384, 256, 0, stream>>>(x, x_bf, 33554432 / 8);
  cast_f32_bf16<<<384, 256, 0, stream>>>(w_qkv, wqkv_bf, 786432 / 8);
  cast_f32_bf16<<<128, 256, 0, stream>>>(w_out, wout_bf, 262144 / 8);

  // Q,K (channels 0..1023), transposed store [bp][c][n]
  gemm_bt<0><<<dim3(512, 8), 256, 0, stream>>>(x_bf, wqkv_bf, b_qkv, QKt);
  // V (channels 1024..1535), natural store [bp][n][c']
  gemm_bt<1><<<dim3(4, 512), 256, 0, stream>>>(wqkv_bf + 1024 * 512, x_bf, b_qkv, V_nat);
  // attention -> Weff
  attn_weff<<<128, 512, 0, stream>>>(QKt, wout_bf, temp, Weff);
  // y[bp][n][co] = Weff[bp] . V[bp]^T + b_out
  gemm_bt<2><<<dim3(4, 32, 16), 256, 0, stream>>>(Weff, V_nat, b_out, y);
}

// Round 2
// 542.766 us; speedup vs baseline: 1.0889x; 1.0889x over previous
//
#include <hip/hip_runtime.h>
#include <stdint.h>

typedef unsigned short u16;
typedef __bf16 bf16x8 __attribute__((ext_vector_type(8)));
typedef float f32x4 __attribute__((ext_vector_type(4)));

#define AS1 __attribute__((address_space(1)))
#define AS3 __attribute__((address_space(3)))

// async global->LDS, 16B per lane; LDS dest is wave-uniform base + lane*16
__device__ __forceinline__ void gload_lds16(u16* lds_wave_base, const u16* g) {
  __builtin_amdgcn_global_load_lds((AS1 void*)g, (AS3 void*)lds_wave_base, 16, 0, 0);
}

__device__ __forceinline__ u16 f2bf(float f) {  // RNE fp32->bf16
  unsigned int u = __float_as_uint(f);
  u += 0x7fffu + ((u >> 16) & 1u);
  return (u16)(u >> 16);
}

// ---------------- cast fp32 -> bf16, 8 elements/thread ----------------
__global__ void cast_f32_bf16(const float* __restrict__ in, u16* __restrict__ out, int n8) {
  int i = blockIdx.x * blockDim.x + threadIdx.x;
  if (i >= n8) return;
  const float4* p = (const float4*)in + (size_t)i * 2;
  float4 a = p[0], b = p[1];
  uint2 lo, hi;
  lo.x = (unsigned)f2bf(a.x) | ((unsigned)f2bf(a.y) << 16);
  lo.y = (unsigned)f2bf(a.z) | ((unsigned)f2bf(a.w) << 16);
  hi.x = (unsigned)f2bf(b.x) | ((unsigned)f2bf(b.y) << 16);
  hi.y = (unsigned)f2bf(b.z) | ((unsigned)f2bf(b.w) << 16);
  uint2* o = (uint2*)out + (size_t)i * 2;
  o[0] = lo;
  o[1] = hi;
}

// ---------------- generic C = A * B^T gemm, M,N mult of 128, K=512 ----------------
// MODE 0: G1a  A=x_bf (M=65536 tokens), B=w_qkv rows 0..1023 (N=1024 ch).
//         grid (8 chblk, 512 tokblk) -> consecutive blocks share A-tile (L2/L3 reuse).
//         store (LDS-transposed): QKt[bp][ch][tok] bf16, 16B/lane contiguous.
//         also: per-channel sum-of-squares -> atomicAdd into ssq[bp*1024+ch].
// MODE 1: G1b  A=w_qkv rows 1024..1535 (M=512 c'), B=x_bf (N=65536 tokens).
//         store (LDS-transposed): V[bp][tok][c'] bf16, 16B/lane contiguous.
// MODE 2: G2   A=Weff[bp] (M=512 co), B=V[bp] (N=4096 tok), grid.z=bp.
//         store: y[bp][tok][co] fp32 + b_out[co], 16B/lane (64B groups).
template <int MODE>
__global__ __launch_bounds__(256) void gemm_bt(const u16* __restrict__ gA,
                                               const u16* __restrict__ gB,
                                               const float* __restrict__ bias,
                                               void* __restrict__ gC,
                                               float* __restrict__ ssq) {
  constexpr int SMEM_U16 = (MODE == 2) ? 8192 : (128 * 136);
  __shared__ __align__(16) u16 smem[SMEM_U16];
  u16* As = smem;
  u16* Bs = smem + 4096;
  const int t = threadIdx.x;
  const int w = t >> 6, l = t & 63;
  const int lrow = l & 15, quad = l >> 4;
  const int wm = (w >> 1) * 64, wn = (w & 1) * 64;
  // MODE 0: x-dim = channel blocks (8), y-dim = token blocks (512) so consecutive
  // blocks share the A (token) tile via L2/L3.
  const int m0 = (MODE == 0 ? blockIdx.y : blockIdx.x) * 128;
  const int n0 = (MODE == 0 ? blockIdx.x : blockIdx.y) * 128;
  const u16* pA = gA;
  const u16* pB = gB;
  if (MODE == 2) {
    pA += (size_t)blockIdx.z * (512 * 512);
    pB += (size_t)blockIdx.z * (4096 * 512);
  }
  // staging geometry: wave w fills LDS rows [w*32, w*32+32), two 1KB issues
  const int srow = w * 32 + (l >> 2);
  const int scol = (l & 3) * 8;
  const u16* ga0 = pA + (size_t)(m0 + srow) * 512 + scol;
  const u16* ga1 = pA + (size_t)(m0 + srow + 16) * 512 + scol;
  const u16* gb0 = pB + (size_t)(n0 + srow) * 512 + scol;
  const u16* gb1 = pB + (size_t)(n0 + srow + 16) * 512 + scol;
  u16* lA0 = &As[w * 1024];
  u16* lA1 = &As[w * 1024 + 512];
  u16* lB0 = &Bs[w * 1024];
  u16* lB1 = &Bs[w * 1024 + 512];

  f32x4 acc[4][4];
#pragma unroll
  for (int mi = 0; mi < 4; ++mi)
#pragma unroll
    for (int ni = 0; ni < 4; ++ni) acc[mi][ni] = (f32x4){0.f, 0.f, 0.f, 0.f};

#pragma unroll 1
  for (int k0 = 0; k0 < 512; k0 += 32) {
    gload_lds16(lA0, ga0 + k0);
    gload_lds16(lA1, ga1 + k0);
    gload_lds16(lB0, gb0 + k0);
    gload_lds16(lB1, gb1 + k0);
    __syncthreads();
    bf16x8 af[4], bfr[4];
#pragma unroll
    for (int mi = 0; mi < 4; ++mi)
      af[mi] = *(const bf16x8*)&As[(wm + mi * 16 + lrow) * 32 + quad * 8];
#pragma unroll
    for (int ni = 0; ni < 4; ++ni)
      bfr[ni] = *(const bf16x8*)&Bs[(wn + ni * 16 + lrow) * 32 + quad * 8];
#pragma unroll
    for (int mi = 0; mi < 4; ++mi)
#pragma unroll
      for (int ni = 0; ni < 4; ++ni)
        acc[mi][ni] = __builtin_amdgcn_mfma_f32_16x16x32_bf16(af[mi], bfr[ni], acc[mi][ni], 0, 0, 0);
    __syncthreads();
  }

  // epilogue: D row (M-dim) = quad*4 + reg, col (N-dim) = lrow  [verified C/D layout]
  if (MODE == 2) {
#pragma unroll
    for (int mi = 0; mi < 4; ++mi) {
      const int mrow = m0 + wm + mi * 16 + quad * 4;
      const float4 bb = *(const float4*)&bias[mrow];
#pragma unroll
      for (int ni = 0; ni < 4; ++ni) {
        const int ncol = n0 + wn + ni * 16 + lrow;
        f32x4 v = acc[mi][ni];
        float4 o;
        o.x = v[0] + bb.x;
        o.y = v[1] + bb.y;
        o.z = v[2] + bb.z;
        o.w = v[3] + bb.w;
        *(float4*)((float*)gC + (((size_t)blockIdx.z * 4096 + ncol) * 512 + mrow)) = o;
      }
    }
  } else {
    // phase 1: bias add (+ sum-of-squares for MODE 0), write bf16 tile to LDS
    // ct[ncol_local][mrow_local], row stride 136 u16 (16B-aligned rows).
    float ss[4] = {0.f, 0.f, 0.f, 0.f};
#pragma unroll
    for (int mi = 0; mi < 4; ++mi) {
      const int mrow_l = wm + mi * 16 + quad * 4;
#pragma unroll
      for (int ni = 0; ni < 4; ++ni) {
        const int ncol_l = wn + ni * 16 + lrow;
        f32x4 v = acc[mi][ni];
        float f0, f1, f2, f3;
        if (MODE == 0) {
          const float bb = bias[n0 + ncol_l];
          f0 = v[0] + bb;
          f1 = v[1] + bb;
          f2 = v[2] + bb;
          f3 = v[3] + bb;
          ss[ni] += f0 * f0 + f1 * f1 + f2 * f2 + f3 * f3;
        } else {
          const float4 bb = *(const float4*)&bias[1024 + m0 + mrow_l];
          f0 = v[0] + bb.x;
          f1 = v[1] + bb.y;
          f2 = v[2] + bb.z;
          f3 = v[3] + bb.w;
        }
        uint2 pk;
        pk.x = (unsigned)f2bf(f0) | ((unsigned)f2bf(f1) << 16);
        pk.y = (unsigned)f2bf(f2) | ((unsigned)f2bf(f3) << 16);
        *(uint2*)&smem[ncol_l * 136 + mrow_l] = pk;
      }
    }
    if (MODE == 0) {
      // reduce SS across the 4 quads holding the same channel, one atomic per channel
#pragma unroll
      for (int ni = 0; ni < 4; ++ni) {
        float s = ss[ni];
        s += __shfl_xor(s, 16);
        s += __shfl_xor(s, 32);
        if (quad == 0)
          atomicAdd(&ssq[((m0 >> 12) << 10) + n0 + wn + ni * 16 + lrow], s);
      }
    }
    __syncthreads();
    // phase 2: 16B/lane fully-coalesced stores, 256B contiguous per output row
    u16* outp = (u16*)gC;
#pragma unroll
    for (int j = 0; j < 8; ++j) {
      const int g = j * 256 + t;   // 0..2047
      const int r = g >> 4;        // local ncol (0..127)
      const int c = (g & 15) * 8;  // local mrow offset
      uint4 val = *(const uint4*)&smem[r * 136 + c];
      size_t gaddr;
      if (MODE == 0) {
        // ncol = channel, mrow = token
        gaddr = ((size_t)(m0 >> 12) << 22) + ((size_t)(n0 + r) << 12) + (size_t)((m0 & 4095) + c);
      } else {
        // ncol = token, mrow = c'
        const int tokg = n0 + r;
        gaddr = (size_t)(tokg >> 12) * (4096 * 512) + (size_t)(tokg & 4095) * 512 + (size_t)(m0 + c);
      }
      *(uint4*)(outp + gaddr) = val;
    }
  }
}

// ---------------- per-(bp,h): QK^T, softmax, Weff = attn^T @ w_out_h ----------------
// QKt: [bp][1024][4096] bf16 (channels 0..511 = q, 512..1023 = k)
// ssq: [bp][1024] fp32 sum-of-squares per channel (from gemm_bt<0>)
// Weff out: [bp][512 co][512 c] bf16, this block fills c in [h*64, h*64+64) for all co.
__global__ __launch_bounds__(512) void attn_weff(const u16* __restrict__ QKt,
                                                 const u16* __restrict__ wout,
                                                 const float* __restrict__ temperature,
                                                 const float* __restrict__ ssq,
                                                 u16* __restrict__ Weff) {
  __shared__ __align__(16) float sattn[64 * 64];
  __shared__ __align__(16) u16 sattnT[64 * 64];
  __shared__ float rn[128];
  const int blk = blockIdx.x;
  const int bp = blk >> 3, h = blk & 7;
  const int t = threadIdx.x, w = t >> 6, l = t & 63;
  const int lrow = l & 15, quad = l >> 4;
  const u16* base = QKt + ((size_t)bp << 22);

  // zero attn accumulator
  for (int i = t; i < 4096; i += 512) sattn[i] = 0.f;

  // reciprocal norms from precomputed sum-of-squares
  if (t < 128) {
    const int ch = (t < 64) ? (h * 64 + t) : (448 + h * 64 + t);
    const float nn = sqrtf(ssq[(bp << 10) + ch]);
    rn[t] = 1.f / fmaxf(nn, 1e-12f);
  }

  // QK^T: each wave covers a 512-token K-chunk; frags straight from global (L2/L3-warm)
  f32x4 acc[4][4];
#pragma unroll
  for (int mi = 0; mi < 4; ++mi)
#pragma unroll
    for (int ni = 0; ni < 4; ++ni) acc[mi][ni] = (f32x4){0.f, 0.f, 0.f, 0.f};
  const u16* qb = base + ((size_t)(h * 64) << 12);
  const u16* kb = base + ((size_t)(512 + h * 64) << 12);
  const int nbase = w * 512;
#pragma unroll 1
  for (int ks = 0; ks < 16; ++ks) {
    const int nn = nbase + ks * 32 + quad * 8;
    bf16x8 af[4], bfr[4];
#pragma unroll
    for (int mi = 0; mi < 4; ++mi)
      af[mi] = *(const bf16x8*)(qb + (((size_t)(mi * 16 + lrow)) << 12) + nn);
#pragma unroll
    for (int ni = 0; ni < 4; ++ni)
      bfr[ni] = *(const bf16x8*)(kb + (((size_t)(ni * 16 + lrow)) << 12) + nn);
#pragma unroll
    for (int mi = 0; mi < 4; ++mi)
#pragma unroll
      for (int ni = 0; ni < 4; ++ni)
        acc[mi][ni] = __builtin_amdgcn_mfma_f32_16x16x32_bf16(af[mi], bfr[ni], acc[mi][ni], 0, 0, 0);
  }
  __syncthreads();  // zeroing + rn complete before accumulation
  // serialized cross-wave reduction into sattn
  for (int ww = 0; ww < 8; ++ww) {
    if (w == ww) {
#pragma unroll
      for (int mi = 0; mi < 4; ++mi)
#pragma unroll
        for (int ni = 0; ni < 4; ++ni)
#pragma unroll
          for (int r = 0; r < 4; ++r)
            sattn[(mi * 16 + quad * 4 + r) * 64 + ni * 16 + lrow] += acc[mi][ni][r];
    }
    __syncthreads();
  }

  // normalize + temperature + softmax over e; write attn^T bf16 (A-operand layout for Weff)
  if (t < 64) {
    const int d = t;
    const float rq = rn[d];
    const float tmp = temperature[h];
    float mx = -1e30f;
    for (int e = 0; e < 64; ++e) {
      const int idx = (e + d) & 63;  // rotate to dodge bank conflicts
      float v = sattn[d * 64 + idx] * rq * rn[64 + idx] * tmp;
      sattn[d * 64 + idx] = v;
      mx = fmaxf(mx, v);
    }
    float s = 0.f;
    for (int e = 0; e < 64; ++e) {
      const int idx = (e + d) & 63;
      float p = __expf(sattn[d * 64 + idx] - mx);
      s += p;
      sattn[d * 64 + idx] = p;
    }
    const float inv = 1.f / s;
    for (int e = 0; e < 64; ++e) sattnT[e * 64 + d] = f2bf(sattn[d * 64 + e] * inv);
  }
  __syncthreads();

  // Weff_h: C[e][co] = sum_d attnT[e][d] * wout[co][h*64+d]  (M=64 e, N=512 co, K=64 d)
  bf16x8 a0[4], a1[4];
#pragma unroll
  for (int mi = 0; mi < 4; ++mi) {
    a0[mi] = *(const bf16x8*)&sattnT[(mi * 16 + lrow) * 64 + quad * 8];
    a1[mi] = *(const bf16x8*)&sattnT[(mi * 16 + lrow) * 64 + 32 + quad * 8];
  }
  u16* wb = Weff + ((size_t)bp * (512 * 512));
#pragma unroll 1
  for (int nb = 0; nb < 4; ++nb) {
    const int co = (w * 4 + nb) * 16 + lrow;
    const u16* wrow = wout + (size_t)co * 512 + h * 64;
    bf16x8 b0 = *(const bf16x8*)(wrow + quad * 8);
    bf16x8 b1 = *(const bf16x8*)(wrow + 32 + quad * 8);
#pragma unroll
    for (int mi = 0; mi < 4; ++mi) {
      f32x4 c = (f32x4){0.f, 0.f, 0.f, 0.f};
      c = __builtin_amdgcn_mfma_f32_16x16x32_bf16(a0[mi], b0, c, 0, 0, 0);
      c = __builtin_amdgcn_mfma_f32_16x16x32_bf16(a1[mi], b1, c, 0, 0, 0);
      const int e0 = mi * 16 + quad * 4;
      uint2 pk;
      pk.x = (unsigned)f2bf(c[0]) | ((unsigned)f2bf(c[1]) << 16);
      pk.y = (unsigned)f2bf(c[2]) | ((unsigned)f2bf(c[3]) << 16);
      *(uint2*)(wb + (size_t)co * 512 + h * 64 + e0) = pk;
    }
  }
}

extern "C" void kernel_launch(void* const* d_in, const int* in_sizes, int n_in,
                              void* d_out, int out_size, void* d_ws, size_t ws_size,
                              hipStream_t stream) {
  const float* x      = (const float*)d_in[0];  // (4,4,4096,512)
  const float* w_qkv  = (const float*)d_in[1];  // (1536,512)
  const float* b_qkv  = (const float*)d_in[2];  // (1536)
  const float* temp   = (const float*)d_in[3];  // (8,1,1)
  const float* w_out  = (const float*)d_in[4];  // (512,512)
  const float* b_out  = (const float*)d_in[5];  // (512)
  float* y = (float*)d_out;

  char* ws = (char*)d_ws;
  u16* x_bf    = (u16*)(ws);                         // 67,108,864 B
  u16* wqkv_bf = (u16*)(ws + 67108864);              //  1,572,864 B
  u16* wout_bf = (u16*)(ws + 68681728);              //    524,288 B
  u16* QKt     = (u16*)(ws + 69206016);              // 134,217,728 B
  u16* V_nat   = (u16*)(ws + 203423744);             // 67,108,864 B
  u16* Weff    = (u16*)(ws + 270532608);             //  8,388,608 B
  float* ssq   = (float*)(ws + 278921216);           //     65,536 B  (end 278,986,752)

  hipMemsetAsync(ssq, 0, 16 * 1024 * sizeof(float), stream);
  cast_f32_bf16<<<16384, 256, 0, stream>>>(x, x_bf, 33554432 / 8);
  cast_f32_bf16<<<384, 256, 0, stream>>>(w_qkv, wqkv_bf, 786432 / 8);
  cast_f32_bf16<<<128, 256, 0, stream>>>(w_out, wout_bf, 262144 / 8);

  // Q,K (channels 0..1023), transposed store [bp][c][n]; grid x=ch-blocks for A reuse
  gemm_bt<0><<<dim3(8, 512), 256, 0, stream>>>(x_bf, wqkv_bf, b_qkv, QKt, ssq);
  // V (channels 1024..1535), natural store [bp][n][c']
  gemm_bt<1><<<dim3(4, 512), 256, 0, stream>>>(wqkv_bf + 1024 * 512, x_bf, b_qkv, V_nat, nullptr);
  // attention -> Weff
  attn_weff<<<128, 512, 0, stream>>>(QKt, wout_bf, temp, ssq, Weff);
  // y[bp][n][co] = Weff[bp] . V[bp]^T + b_out
  gemm_bt<2><<<dim3(4, 32, 16), 256, 0, stream>>>(Weff, V_nat, b_out, y, nullptr);
}

// Round 3
// 518.817 us; speedup vs baseline: 1.1392x; 1.0462x over previous
//
#include <hip/hip_runtime.h>
#include <stdint.h>

typedef unsigned short u16;
typedef __bf16 bf16x8 __attribute__((ext_vector_type(8)));
typedef float f32x4 __attribute__((ext_vector_type(4)));

#define AS1 __attribute__((address_space(1)))
#define AS3 __attribute__((address_space(3)))

// async global->LDS, 16B per lane; LDS dest is wave-uniform base + lane*16
__device__ __forceinline__ void gload_lds16(u16* lds_wave_base, const u16* g) {
  __builtin_amdgcn_global_load_lds((AS1 void*)g, (AS3 void*)lds_wave_base, 16, 0, 0);
}

__device__ __forceinline__ u16 f2bf(float f) {  // RNE fp32->bf16
  unsigned int u = __float_as_uint(f);
  u += 0x7fffu + ((u >> 16) & 1u);
  return (u16)(u >> 16);
}

// ---------------- cast fp32 -> bf16, 8 elements/thread ----------------
__global__ void cast_f32_bf16(const float* __restrict__ in, u16* __restrict__ out, int n8) {
  int i = blockIdx.x * blockDim.x + threadIdx.x;
  if (i >= n8) return;
  const float4* p = (const float4*)in + (size_t)i * 2;
  float4 a = p[0], b = p[1];
  uint2 lo, hi;
  lo.x = (unsigned)f2bf(a.x) | ((unsigned)f2bf(a.y) << 16);
  lo.y = (unsigned)f2bf(a.z) | ((unsigned)f2bf(a.w) << 16);
  hi.x = (unsigned)f2bf(b.x) | ((unsigned)f2bf(b.y) << 16);
  hi.y = (unsigned)f2bf(b.z) | ((unsigned)f2bf(b.w) << 16);
  uint2* o = (uint2*)out + (size_t)i * 2;
  o[0] = lo;
  o[1] = hi;
}

// ---------------- generic C = A * B^T gemm, K=512, 1D grid, XCD-swizzled ----------------
// MODE 0: G1a  A=x_bf (M=65536 tok), B=w_qkv rows 0..1023 (N=1024 ch). grid 4096.
//         swizzle: 8 ch-blocks sharing a token A-tile land on ONE XCD (id%8 const).
//         store (LDS-transposed): QKt[bp][ch][tok] bf16 + ssq atomics.
// MODE 1: G1b  A=w_qkv rows 1024..1535 (M=512 c'), B=x_bf (N=65536 tok). grid 2048.
//         swizzle: 4 m-blocks sharing a token B-tile on one XCD.
//         store (LDS-transposed): V[bp][tok][c'] bf16.
// MODE 2: G2   A=Weff[bp] (M=512 co), B=V[bp] (N=4096 tok). grid 2048 (bp = id>>7).
//         store: y[bp][tok][co] fp32 + b_out, LDS-transposed in two fp32 half-tiles.
template <int MODE>
__global__ __launch_bounds__(256) void gemm_bt(const u16* __restrict__ gA,
                                               const u16* __restrict__ gB,
                                               const float* __restrict__ bias,
                                               void* __restrict__ gC,
                                               float* __restrict__ ssq) {
  __shared__ __align__(16) u16 smem[128 * 136];  // 34816 B
  u16* As = smem;
  u16* Bs = smem + 4096;
  const int t = threadIdx.x;
  const int w = t >> 6, l = t & 63;
  const int lrow = l & 15, quad = l >> 4;
  const int wm = (w >> 1) * 64, wn = (w & 1) * 64;
  int m0, n0, zz = 0;
  if (MODE == 0) {
    const int b = blockIdx.x;  // 4096
    const int ch = (b >> 3) & 7;
    const int T = ((b >> 6) << 3) | (b & 7);  // token tile 0..511; id%8 == T&7
    m0 = T * 128;
    n0 = ch * 128;
  } else if (MODE == 1) {
    const int b = blockIdx.x;  // 2048
    const int j = (b >> 3) & 3;
    const int T = ((b >> 5) << 3) | (b & 7);  // token tile 0..511
    m0 = j * 128;
    n0 = T * 128;
  } else {
    const int b = blockIdx.x;  // 2048
    const int local = b & 127;
    zz = b >> 7;
    const int j = (local >> 3) & 3;
    const int T = ((local >> 5) << 3) | (local & 7);  // token tile 0..31
    m0 = j * 128;
    n0 = T * 128;
  }
  const u16* pA = gA;
  const u16* pB = gB;
  if (MODE == 2) {
    pA += (size_t)zz * (512 * 512);
    pB += (size_t)zz * (4096 * 512);
  }
  // staging geometry: wave w fills LDS rows [w*32, w*32+32), two 1KB issues
  const int srow = w * 32 + (l >> 2);
  const int scol = (l & 3) * 8;
  const u16* ga0 = pA + (size_t)(m0 + srow) * 512 + scol;
  const u16* ga1 = pA + (size_t)(m0 + srow + 16) * 512 + scol;
  const u16* gb0 = pB + (size_t)(n0 + srow) * 512 + scol;
  const u16* gb1 = pB + (size_t)(n0 + srow + 16) * 512 + scol;
  u16* lA0 = &As[w * 1024];
  u16* lA1 = &As[w * 1024 + 512];
  u16* lB0 = &Bs[w * 1024];
  u16* lB1 = &Bs[w * 1024 + 512];

  f32x4 acc[4][4];
#pragma unroll
  for (int mi = 0; mi < 4; ++mi)
#pragma unroll
    for (int ni = 0; ni < 4; ++ni) acc[mi][ni] = (f32x4){0.f, 0.f, 0.f, 0.f};

#pragma unroll 1
  for (int k0 = 0; k0 < 512; k0 += 32) {
    gload_lds16(lA0, ga0 + k0);
    gload_lds16(lA1, ga1 + k0);
    gload_lds16(lB0, gb0 + k0);
    gload_lds16(lB1, gb1 + k0);
    __syncthreads();
    bf16x8 af[4], bfr[4];
#pragma unroll
    for (int mi = 0; mi < 4; ++mi)
      af[mi] = *(const bf16x8*)&As[(wm + mi * 16 + lrow) * 32 + quad * 8];
#pragma unroll
    for (int ni = 0; ni < 4; ++ni)
      bfr[ni] = *(const bf16x8*)&Bs[(wn + ni * 16 + lrow) * 32 + quad * 8];
#pragma unroll
    for (int mi = 0; mi < 4; ++mi)
#pragma unroll
      for (int ni = 0; ni < 4; ++ni)
        acc[mi][ni] = __builtin_amdgcn_mfma_f32_16x16x32_bf16(af[mi], bfr[ni], acc[mi][ni], 0, 0, 0);
    __syncthreads();
  }

  // epilogue: D row (M-dim) = quad*4 + reg, col (N-dim) = lrow  [verified C/D layout]
  if (MODE == 2) {
    // two fp32 half-tiles (64 ncol each) through LDS, pad 136 floats (16B-aligned rows)
    float* fs = (float*)smem;
#pragma unroll
    for (int half = 0; half < 2; ++half) {
      if (half) __syncthreads();
#pragma unroll
      for (int mi = 0; mi < 4; ++mi) {
        const int mrow_l = wm + mi * 16 + quad * 4;
        const float4 bb = *(const float4*)&bias[m0 + mrow_l];
#pragma unroll
        for (int ni = 0; ni < 4; ++ni) {
          const int ncol_l = wn + ni * 16 + lrow;
          if ((ncol_l >> 6) != half) continue;
          f32x4 v = acc[mi][ni];
          float4 o;
          o.x = v[0] + bb.x;
          o.y = v[1] + bb.y;
          o.z = v[2] + bb.z;
          o.w = v[3] + bb.w;
          *(float4*)&fs[(ncol_l & 63) * 136 + mrow_l] = o;
        }
      }
      __syncthreads();
#pragma unroll
      for (int j2 = 0; j2 < 4; ++j2) {
        const int g = j2 * 256 + t;  // 0..1023
        const int r = g >> 4;        // local token row 0..63
        const int c = (g & 15) * 8;  // co offset, 32B per lane
        float4 v0 = *(const float4*)&fs[r * 136 + c];
        float4 v1 = *(const float4*)&fs[r * 136 + c + 4];
        float* yp = (float*)gC + (((size_t)zz * 4096 + n0 + half * 64 + r) * 512 + m0 + c);
        *(float4*)yp = v0;
        *(float4*)(yp + 4) = v1;
      }
    }
  } else {
    // phase 1: bias add (+ sum-of-squares for MODE 0), write bf16 tile to LDS
    float ss[4] = {0.f, 0.f, 0.f, 0.f};
#pragma unroll
    for (int mi = 0; mi < 4; ++mi) {
      const int mrow_l = wm + mi * 16 + quad * 4;
#pragma unroll
      for (int ni = 0; ni < 4; ++ni) {
        const int ncol_l = wn + ni * 16 + lrow;
        f32x4 v = acc[mi][ni];
        float f0, f1, f2, f3;
        if (MODE == 0) {
          const float bb = bias[n0 + ncol_l];
          f0 = v[0] + bb;
          f1 = v[1] + bb;
          f2 = v[2] + bb;
          f3 = v[3] + bb;
          ss[ni] += f0 * f0 + f1 * f1 + f2 * f2 + f3 * f3;
        } else {
          const float4 bb = *(const float4*)&bias[1024 + m0 + mrow_l];
          f0 = v[0] + bb.x;
          f1 = v[1] + bb.y;
          f2 = v[2] + bb.z;
          f3 = v[3] + bb.w;
        }
        uint2 pk;
        pk.x = (unsigned)f2bf(f0) | ((unsigned)f2bf(f1) << 16);
        pk.y = (unsigned)f2bf(f2) | ((unsigned)f2bf(f3) << 16);
        *(uint2*)&smem[ncol_l * 136 + mrow_l] = pk;
      }
    }
    if (MODE == 0) {
#pragma unroll
      for (int ni = 0; ni < 4; ++ni) {
        float s = ss[ni];
        s += __shfl_xor(s, 16);
        s += __shfl_xor(s, 32);
        if (quad == 0)
          atomicAdd(&ssq[((m0 >> 12) << 10) + n0 + wn + ni * 16 + lrow], s);
      }
    }
    __syncthreads();
    // phase 2: 16B/lane fully-coalesced stores, 256B contiguous per output row
    u16* outp = (u16*)gC;
#pragma unroll
    for (int j = 0; j < 8; ++j) {
      const int g = j * 256 + t;   // 0..2047
      const int r = g >> 4;        // local ncol (0..127)
      const int c = (g & 15) * 8;  // local mrow offset
      uint4 val = *(const uint4*)&smem[r * 136 + c];
      size_t gaddr;
      if (MODE == 0) {
        gaddr = ((size_t)(m0 >> 12) << 22) + ((size_t)(n0 + r) << 12) + (size_t)((m0 & 4095) + c);
      } else {
        const int tokg = n0 + r;
        gaddr = (size_t)(tokg >> 12) * (4096 * 512) + (size_t)(tokg & 4095) * 512 + (size_t)(m0 + c);
      }
      *(uint4*)(outp + gaddr) = val;
    }
  }
}

// ---------------- QK^T partials: grid 1024 = (bp,h) x 8 token-chunks ----------------
// part[(bp*8+h)*8 + chunk][4096] fp32 = 64x64 partial of raw q.k over 512 tokens
__global__ __launch_bounds__(256) void qk_partial(const u16* __restrict__ QKt,
                                                  float* __restrict__ part) {
  __shared__ __align__(16) float sred[64 * 64];
  const int b = blockIdx.x;
  const int chunk = b & 7, blk = b >> 3;  // blk = bp*8+h
  const int bp = blk >> 3, h = blk & 7;
  const int t = threadIdx.x, w = t >> 6, l = t & 63;
  const int lrow = l & 15, quad = l >> 4;
  const u16* base = QKt + ((size_t)bp << 22);
  const u16* qb = base + ((size_t)(h * 64) << 12);
  const u16* kb = base + ((size_t)(512 + h * 64) << 12);
  f32x4 acc[4][4];
#pragma unroll
  for (int mi = 0; mi < 4; ++mi)
#pragma unroll
    for (int ni = 0; ni < 4; ++ni) acc[mi][ni] = (f32x4){0.f, 0.f, 0.f, 0.f};
  const int nbase = chunk * 512 + w * 128;
#pragma unroll 1
  for (int ks = 0; ks < 4; ++ks) {
    const int nn = nbase + ks * 32 + quad * 8;
    bf16x8 af[4], bfr[4];
#pragma unroll
    for (int mi = 0; mi < 4; ++mi)
      af[mi] = *(const bf16x8*)(qb + (((size_t)(mi * 16 + lrow)) << 12) + nn);
#pragma unroll
    for (int ni = 0; ni < 4; ++ni)
      bfr[ni] = *(const bf16x8*)(kb + (((size_t)(ni * 16 + lrow)) << 12) + nn);
#pragma unroll
    for (int mi = 0; mi < 4; ++mi)
#pragma unroll
      for (int ni = 0; ni < 4; ++ni)
        acc[mi][ni] = __builtin_amdgcn_mfma_f32_16x16x32_bf16(af[mi], bfr[ni], acc[mi][ni], 0, 0, 0);
  }
  __syncthreads();
  for (int ww = 0; ww < 4; ++ww) {
    if (w == ww) {
#pragma unroll
      for (int mi = 0; mi < 4; ++mi)
#pragma unroll
        for (int ni = 0; ni < 4; ++ni)
#pragma unroll
          for (int r = 0; r < 4; ++r) {
            const int idx = (mi * 16 + quad * 4 + r) * 64 + ni * 16 + lrow;
            if (ww == 0)
              sred[idx] = acc[mi][ni][r];
            else
              sred[idx] += acc[mi][ni][r];
          }
    }
    __syncthreads();
  }
  float4* dst = (float4*)(part + ((size_t)blk * 8 + chunk) * 4096);
  const float4* src = (const float4*)sred;
  for (int i = t; i < 1024; i += 256) dst[i] = src[i];
}

// ---------------- per-(bp,h): sum partials, norms, softmax, Weff ----------------
__global__ __launch_bounds__(512) void softmax_weff(const float* __restrict__ part,
                                                    const u16* __restrict__ wout,
                                                    const float* __restrict__ temperature,
                                                    const float* __restrict__ ssq,
                                                    u16* __restrict__ Weff) {
  __shared__ __align__(16) float sattn[64 * 64];
  __shared__ __align__(16) u16 sattnT[64 * 64];
  __shared__ float rn[128];
  const int blk = blockIdx.x;
  const int bp = blk >> 3, h = blk & 7;
  const int t = threadIdx.x, w = t >> 6, l = t & 63;
  const int lrow = l & 15, quad = l >> 4;

  // sum the 8 token-chunk partials
  const float4* pbase = (const float4*)(part + (size_t)blk * 8 * 4096);
  for (int i = t; i < 1024; i += 512) {
    float4 s0 = pbase[i];
#pragma unroll
    for (int p = 1; p < 8; ++p) {
      float4 sp = pbase[p * 1024 + i];
      s0.x += sp.x;
      s0.y += sp.y;
      s0.z += sp.z;
      s0.w += sp.w;
    }
    ((float4*)sattn)[i] = s0;
  }

  // reciprocal norms from precomputed sum-of-squares
  if (t < 128) {
    const int ch = (t < 64) ? (h * 64 + t) : (448 + h * 64 + t);
    const float nn = sqrtf(ssq[(bp << 10) + ch]);
    rn[t] = 1.f / fmaxf(nn, 1e-12f);
  }
  __syncthreads();

  // normalize + temperature + softmax over e; write attn^T bf16 (A-operand layout)
  if (t < 64) {
    const int d = t;
    const float rq = rn[d];
    const float tmp = temperature[h];
    float mx = -1e30f;
    for (int e = 0; e < 64; ++e) {
      const int idx = (e + d) & 63;  // rotate to dodge bank conflicts
      float v = sattn[d * 64 + idx] * rq * rn[64 + idx] * tmp;
      sattn[d * 64 + idx] = v;
      mx = fmaxf(mx, v);
    }
    float s = 0.f;
    for (int e = 0; e < 64; ++e) {
      const int idx = (e + d) & 63;
      float p = __expf(sattn[d * 64 + idx] - mx);
      s += p;
      sattn[d * 64 + idx] = p;
    }
    const float inv = 1.f / s;
    for (int e = 0; e < 64; ++e) sattnT[e * 64 + d] = f2bf(sattn[d * 64 + e] * inv);
  }
  __syncthreads();

  // Weff_h: C[e][co] = sum_d attnT[e][d] * wout[co][h*64+d]  (M=64 e, N=512 co, K=64 d)
  bf16x8 a0[4], a1[4];
#pragma unroll
  for (int mi = 0; mi < 4; ++mi) {
    a0[mi] = *(const bf16x8*)&sattnT[(mi * 16 + lrow) * 64 + quad * 8];
    a1[mi] = *(const bf16x8*)&sattnT[(mi * 16 + lrow) * 64 + 32 + quad * 8];
  }
  u16* wb = Weff + ((size_t)bp * (512 * 512));
#pragma unroll 1
  for (int nb = 0; nb < 4; ++nb) {
    const int co = (w * 4 + nb) * 16 + lrow;
    const u16* wrow = wout + (size_t)co * 512 + h * 64;
    bf16x8 b0 = *(const bf16x8*)(wrow + quad * 8);
    bf16x8 b1 = *(const bf16x8*)(wrow + 32 + quad * 8);
#pragma unroll
    for (int mi = 0; mi < 4; ++mi) {
      f32x4 c = (f32x4){0.f, 0.f, 0.f, 0.f};
      c = __builtin_amdgcn_mfma_f32_16x16x32_bf16(a0[mi], b0, c, 0, 0, 0);
      c = __builtin_amdgcn_mfma_f32_16x16x32_bf16(a1[mi], b1, c, 0, 0, 0);
      const int e0 = mi * 16 + quad * 4;
      uint2 pk;
      pk.x = (unsigned)f2bf(c[0]) | ((unsigned)f2bf(c[1]) << 16);
      pk.y = (unsigned)f2bf(c[2]) | ((unsigned)f2bf(c[3]) << 16);
      *(uint2*)(wb + (size_t)co * 512 + h * 64 + e0) = pk;
    }
  }
}

extern "C" void kernel_launch(void* const* d_in, const int* in_sizes, int n_in,
                              void* d_out, int out_size, void* d_ws, size_t ws_size,
                              hipStream_t stream) {
  const float* x      = (const float*)d_in[0];  // (4,4,4096,512)
  const float* w_qkv  = (const float*)d_in[1];  // (1536,512)
  const float* b_qkv  = (const float*)d_in[2];  // (1536)
  const float* temp   = (const float*)d_in[3];  // (8,1,1)
  const float* w_out  = (const float*)d_in[4];  // (512,512)
  const float* b_out  = (const float*)d_in[5];  // (512)
  float* y = (float*)d_out;

  char* ws = (char*)d_ws;
  u16* x_bf    = (u16*)(ws);                         // 67,108,864 B
  u16* wqkv_bf = (u16*)(ws + 67108864);              //  1,572,864 B
  u16* wout_bf = (u16*)(ws + 68681728);              //    524,288 B
  u16* QKt     = (u16*)(ws + 69206016);              // 134,217,728 B
  u16* V_nat   = (u16*)(ws + 203423744);             // 67,108,864 B
  u16* Weff    = (u16*)(ws + 270532608);             //  8,388,608 B
  float* ssq   = (float*)(ws + 278921216);           //     65,536 B
  // qk partials (16 MB) alias x_bf: x_bf's last reader is gemm_bt<1>, which
  // runs before qk_partial in this stream.
  float* part  = (float*)(ws);

  hipMemsetAsync(ssq, 0, 16 * 1024 * sizeof(float), stream);
  cast_f32_bf16<<<16384, 256, 0, stream>>>(x, x_bf, 33554432 / 8);
  cast_f32_bf16<<<384, 256, 0, stream>>>(w_qkv, wqkv_bf, 786432 / 8);
  cast_f32_bf16<<<128, 256, 0, stream>>>(w_out, wout_bf, 262144 / 8);

  // Q,K (channels 0..1023), transposed store [bp][c][n], XCD-swizzled
  gemm_bt<0><<<4096, 256, 0, stream>>>(x_bf, wqkv_bf, b_qkv, QKt, ssq);
  // V (channels 1024..1535), natural store [bp][n][c'], XCD-swizzled
  gemm_bt<1><<<2048, 256, 0, stream>>>(wqkv_bf + 1024 * 512, x_bf, b_qkv, V_nat, nullptr);
  // QK^T partials (after gemm1: part aliases x_bf)
  qk_partial<<<1024, 256, 0, stream>>>(QKt, part);
  // softmax + Weff
  softmax_weff<<<128, 512, 0, stream>>>(part, wout_bf, temp, ssq, Weff);
  // y[bp][n][co] = Weff[bp] . V[bp]^T + b_out
  gemm_bt<2><<<2048, 256, 0, stream>>>(Weff, V_nat, b_out, y, nullptr);
}